// Round 3
// baseline (75.968 us; speedup 1.0000x reference)
//
#include <hip/hip_runtime.h>
#include <math.h>

static constexpr int N   = 4096;  // IN_SIZE
static constexpr int H   = 5;     // HID
static constexpr int NO  = 2048;  // OUT_SIZE
static constexpr float FEPS = 1e-4f;
static constexpr int RPB  = 8;        // X rows per block in k_xw1
static constexpr int NBLK = N / RPB;  // 512

// ws layout (floats):
// [0        , NBLK*25)      : Mp  per-block partial M (5x5 each)
// [NBLK*25  , NBLK*25 + 25) : yp  = y - eps*I  (5x5)

__device__ __forceinline__ float wave_reduce(float v) {
#pragma unroll
    for (int o = 32; o > 0; o >>= 1) v += __shfl_down(v, o, 64);
    return v;
}

// Per-block partial of M = W1^T (X W1): each block handles 8 rows of X,
// folds its per-thread partial T directly into a 5x5 partial M (linearity),
// reduces across the block, writes 25 floats. No T array at all.
__global__ __launch_bounds__(256) void k_xw1(const float* __restrict__ X,
                                             const float* __restrict__ W1,
                                             float* __restrict__ Mp) {
    const int rb = blockIdx.x * RPB;
    const int t  = threadIdx.x;
    const float4* W14 = reinterpret_cast<const float4*>(W1);

    float acc[RPB][H];
#pragma unroll
    for (int r = 0; r < RPB; ++r)
#pragma unroll
        for (int a = 0; a < H; ++a) acc[r][a] = 0.f;

#pragma unroll
    for (int c = 0; c < 4; ++c) {
        const int j4 = c * 256 + t;   // float4 idx within row; W1 rows 4j4..4j4+3
        float wf[20];
        {
            const float4 f0 = W14[5 * j4 + 0];
            const float4 f1 = W14[5 * j4 + 1];
            const float4 f2 = W14[5 * j4 + 2];
            const float4 f3 = W14[5 * j4 + 3];
            const float4 f4 = W14[5 * j4 + 4];
            wf[0]=f0.x;  wf[1]=f0.y;  wf[2]=f0.z;  wf[3]=f0.w;
            wf[4]=f1.x;  wf[5]=f1.y;  wf[6]=f1.z;  wf[7]=f1.w;
            wf[8]=f2.x;  wf[9]=f2.y;  wf[10]=f2.z; wf[11]=f2.w;
            wf[12]=f3.x; wf[13]=f3.y; wf[14]=f3.z; wf[15]=f3.w;
            wf[16]=f4.x; wf[17]=f4.y; wf[18]=f4.z; wf[19]=f4.w;
        }
#pragma unroll
        for (int r = 0; r < RPB; ++r) {
            const float4 x = reinterpret_cast<const float4*>(
                                 X + (size_t)(rb + r) * N)[j4];
#pragma unroll
            for (int a = 0; a < H; ++a)
                acc[r][a] += x.x * wf[a]      + x.y * wf[5 + a]
                           + x.z * wf[10 + a] + x.w * wf[15 + a];
        }
    }

    // fold per-thread partial T rows into per-thread partial M (W1 loads are
    // block-uniform -> scalar loads)
    float m[H][H];
#pragma unroll
    for (int a = 0; a < H; ++a)
#pragma unroll
        for (int b = 0; b < H; ++b) m[a][b] = 0.f;
#pragma unroll
    for (int r = 0; r < RPB; ++r) {
        float w1r[H];
#pragma unroll
        for (int a = 0; a < H; ++a) w1r[a] = W1[(size_t)(rb + r) * H + a];
#pragma unroll
        for (int a = 0; a < H; ++a)
#pragma unroll
            for (int b = 0; b < H; ++b) m[a][b] += w1r[a] * acc[r][b];
    }

    // block reduce (fixed order, deterministic)
    __shared__ float sm[4][25];
    const int lane = t & 63, wv = t >> 6;
#pragma unroll
    for (int a = 0; a < H; ++a)
#pragma unroll
        for (int b = 0; b < H; ++b) {
            const float v = wave_reduce(m[a][b]);
            if (lane == 0) sm[wv][a * H + b] = v;
        }
    __syncthreads();
    if (t < 25)
        Mp[blockIdx.x * 25 + t] = sm[0][t] + sm[1][t] + sm[2][t] + sm[3][t];
}

// Fully-register f32 Jacobi: compile-time (p,q) so A/Uv stay in VGPRs.
#define JROT(p, q)                                                            \
    {                                                                         \
        const float apq = A[p][q];                                            \
        const float app = A[p][p], aqq = A[q][q];                             \
        const bool skip =                                                     \
            (apq * apq) <= (1e-28f * (app * app + aqq * aqq) + 1e-38f);       \
        const float theta = (aqq - app) / (2.0f * apq);                       \
        const float tden  = fabsf(theta) + sqrtf(theta * theta + 1.0f);       \
        const float ttv   = ((theta >= 0.0f) ? 1.0f : -1.0f) / tden;          \
        float cc = 1.0f / sqrtf(ttv * ttv + 1.0f);                            \
        float ss = ttv * cc;                                                  \
        cc = skip ? 1.0f : cc;                                                \
        ss = skip ? 0.0f : ss;                                                \
        _Pragma("unroll") for (int k = 0; k < H; ++k) {                       \
            const float apk = A[p][k], aqk = A[q][k];                         \
            A[p][k] = cc * apk - ss * aqk;                                    \
            A[q][k] = ss * apk + cc * aqk;                                    \
        }                                                                     \
        _Pragma("unroll") for (int k = 0; k < H; ++k) {                       \
            const float akp = A[k][p], akq = A[k][q];                         \
            A[k][p] = cc * akp - ss * akq;                                    \
            A[k][q] = ss * akp + cc * akq;                                    \
        }                                                                     \
        _Pragma("unroll") for (int k = 0; k < H; ++k) {                       \
            const float ukp = Uv[k][p], ukq = Uv[k][q];                       \
            Uv[k][p] = cc * ukp - ss * ukq;                                   \
            Uv[k][q] = ss * ukp + cc * ukq;                                   \
        }                                                                     \
    }

#define JSWEEP                                                                \
    JROT(0, 1) JROT(0, 2) JROT(0, 3) JROT(0, 4) JROT(1, 2)                    \
    JROT(1, 3) JROT(1, 4) JROT(2, 3) JROT(2, 4) JROT(3, 4)

// One block: reduce 512 partial Ms -> M; eig(M M^T) via register Jacobi;
// yp = U max(sqrt(lam),eps) U^T - eps*I (25 floats).
__global__ __launch_bounds__(256) void k_small(const float* __restrict__ Mp,
                                               float* __restrict__ yp) {
    __shared__ float sred[10][25];
    __shared__ float Msum[25];
    const int t = threadIdx.x;

    if (t < 250) {
        const int e = t % 25, g = t / 25;
        float s = 0.f;
        for (int p = g; p < NBLK; p += 10) s += Mp[p * 25 + e];
        sred[g][e] = s;
    }
    __syncthreads();
    if (t < 25) {
        float s = 0.f;
#pragma unroll
        for (int g = 0; g < 10; ++g) s += sred[g][t];
        Msum[t] = s;
    }
    __syncthreads();

    if (t == 0) {
        float Md[H][H];
#pragma unroll
        for (int a = 0; a < H; ++a)
#pragma unroll
            for (int b = 0; b < H; ++b) Md[a][b] = Msum[a * H + b];

        float A[H][H], Uv[H][H];
#pragma unroll
        for (int a = 0; a < H; ++a)
#pragma unroll
            for (int b = 0; b < H; ++b) {
                float s = 0.f;
#pragma unroll
                for (int k = 0; k < H; ++k) s += Md[a][k] * Md[b][k];
                A[a][b] = s;
                Uv[a][b] = (a == b) ? 1.0f : 0.0f;
            }

        JSWEEP JSWEEP JSWEEP JSWEEP JSWEEP JSWEEP JSWEEP JSWEEP  // 8 sweeps

        float ev[H];
#pragma unroll
        for (int k = 0; k < H; ++k) {
            const float lam = fmaxf(A[k][k], 0.0f);
            ev[k] = fmaxf(sqrtf(lam), FEPS);
        }
#pragma unroll
        for (int a = 0; a < H; ++a)
#pragma unroll
            for (int b = 0; b < H; ++b) {
                float s = 0.f;
#pragma unroll
                for (int k = 0; k < H; ++k) s += Uv[a][k] * ev[k] * Uv[b][k];
                yp[a * H + b] = s - ((a == b) ? FEPS : 0.f);
            }
    }
}

// z[i][j] = sum_m c[m]*W2[m][j] + eps*delta_ij,  c[m] = sum_k W2[k][i]*yp[k][m]
// One block per row i; yp/W2-column loads are block-uniform (scalar).
__global__ __launch_bounds__(256) void k_out(const float* __restrict__ W2,
                                             const float* __restrict__ yp,
                                             float* __restrict__ Z) {
    const int i = blockIdx.x;
    const int t = threadIdx.x;

    float wcol[H];
#pragma unroll
    for (int k = 0; k < H; ++k) wcol[k] = W2[(size_t)k * NO + i];
    float c[H];
#pragma unroll
    for (int m = 0; m < H; ++m) {
        float s = 0.f;
#pragma unroll
        for (int k = 0; k < H; ++k) s += wcol[k] * yp[k * H + m];
        c[m] = s;
    }

#pragma unroll
    for (int hh = 0; hh < 2; ++hh) {
        const int jj = (hh * 256 + t) * 4;
        float zx = 0.f, zy = 0.f, zz = 0.f, zw = 0.f;
#pragma unroll
        for (int m = 0; m < H; ++m) {
            const float4 b = *reinterpret_cast<const float4*>(W2 + (size_t)m * NO + jj);
            zx += c[m] * b.x;
            zy += c[m] * b.y;
            zz += c[m] * b.z;
            zw += c[m] * b.w;
        }
        zx += (i == jj + 0) ? FEPS : 0.f;
        zy += (i == jj + 1) ? FEPS : 0.f;
        zz += (i == jj + 2) ? FEPS : 0.f;
        zw += (i == jj + 3) ? FEPS : 0.f;
        float4 o = make_float4(zx, zy, zz, zw);
        *reinterpret_cast<float4*>(Z + (size_t)i * NO + jj) = o;
    }
}

extern "C" void kernel_launch(void* const* d_in, const int* in_sizes, int n_in,
                              void* d_out, int out_size, void* d_ws, size_t ws_size,
                              hipStream_t stream) {
    const float* X  = (const float*)d_in[0];
    const float* W1 = (const float*)d_in[1];
    const float* W2 = (const float*)d_in[2];
    float* out = (float*)d_out;
    float* ws  = (float*)d_ws;

    float* Mp = ws;              // NBLK*25
    float* yp = ws + NBLK * 25;  // 25

    hipLaunchKernelGGL(k_xw1,   dim3(NBLK), dim3(256), 0, stream, X, W1, Mp);
    hipLaunchKernelGGL(k_small, dim3(1),    dim3(256), 0, stream, Mp, yp);
    hipLaunchKernelGGL(k_out,   dim3(NO),   dim3(256), 0, stream, W2, yp, out);
}

// Round 4
// 48.394 us; speedup vs baseline: 1.5698x; 1.5698x over previous
//
#include <hip/hip_runtime.h>
#include <math.h>

static constexpr int N   = 4096;  // IN_SIZE
static constexpr int H   = 5;     // HID
static constexpr int NO  = 2048;  // OUT_SIZE
static constexpr float FEPS = 1e-4f;
static constexpr int RPB  = 8;        // X rows per block in k_xw1
static constexpr int NBLK = N / RPB;  // 512

#if __has_builtin(__builtin_amdgcn_rcpf)
__device__ __forceinline__ float frcp(float x) { return __builtin_amdgcn_rcpf(x); }
#else
__device__ __forceinline__ float frcp(float x) { return 1.0f / x; }
#endif
#if __has_builtin(__builtin_amdgcn_rsqf)
__device__ __forceinline__ float frsq(float x) { return __builtin_amdgcn_rsqf(x); }
#else
__device__ __forceinline__ float frsq(float x) { return 1.0f / sqrtf(x); }
#endif

__device__ __forceinline__ float wave_reduce(float v) {
#pragma unroll
    for (int o = 32; o > 0; o >>= 1) v += __shfl_down(v, o, 64);
    return v;
}

// Per-block partial of M = W1^T (X W1): each block handles 8 rows of X,
// folds its per-thread partial T directly into a 5x5 partial M (linearity),
// reduces across the block, writes 25 floats. No T array at all.
__global__ __launch_bounds__(256) void k_xw1(const float* __restrict__ X,
                                             const float* __restrict__ W1,
                                             float* __restrict__ Mp) {
    const int rb = blockIdx.x * RPB;
    const int t  = threadIdx.x;
    const float4* W14 = reinterpret_cast<const float4*>(W1);

    float acc[RPB][H];
#pragma unroll
    for (int r = 0; r < RPB; ++r)
#pragma unroll
        for (int a = 0; a < H; ++a) acc[r][a] = 0.f;

#pragma unroll
    for (int c = 0; c < 4; ++c) {
        const int j4 = c * 256 + t;   // float4 idx within row; W1 rows 4j4..4j4+3
        float wf[20];
        {
            const float4 f0 = W14[5 * j4 + 0];
            const float4 f1 = W14[5 * j4 + 1];
            const float4 f2 = W14[5 * j4 + 2];
            const float4 f3 = W14[5 * j4 + 3];
            const float4 f4 = W14[5 * j4 + 4];
            wf[0]=f0.x;  wf[1]=f0.y;  wf[2]=f0.z;  wf[3]=f0.w;
            wf[4]=f1.x;  wf[5]=f1.y;  wf[6]=f1.z;  wf[7]=f1.w;
            wf[8]=f2.x;  wf[9]=f2.y;  wf[10]=f2.z; wf[11]=f2.w;
            wf[12]=f3.x; wf[13]=f3.y; wf[14]=f3.z; wf[15]=f3.w;
            wf[16]=f4.x; wf[17]=f4.y; wf[18]=f4.z; wf[19]=f4.w;
        }
#pragma unroll
        for (int r = 0; r < RPB; ++r) {
            const float4 x = reinterpret_cast<const float4*>(
                                 X + (size_t)(rb + r) * N)[j4];
#pragma unroll
            for (int a = 0; a < H; ++a)
                acc[r][a] += x.x * wf[a]      + x.y * wf[5 + a]
                           + x.z * wf[10 + a] + x.w * wf[15 + a];
        }
    }

    // fold per-thread partial T rows into per-thread partial M (W1 loads are
    // block-uniform -> scalar loads)
    float m[H][H];
#pragma unroll
    for (int a = 0; a < H; ++a)
#pragma unroll
        for (int b = 0; b < H; ++b) m[a][b] = 0.f;
#pragma unroll
    for (int r = 0; r < RPB; ++r) {
        float w1r[H];
#pragma unroll
        for (int a = 0; a < H; ++a) w1r[a] = W1[(size_t)(rb + r) * H + a];
#pragma unroll
        for (int a = 0; a < H; ++a)
#pragma unroll
            for (int b = 0; b < H; ++b) m[a][b] += w1r[a] * acc[r][b];
    }

    __shared__ float sm[4][25];
    const int lane = t & 63, wv = t >> 6;
#pragma unroll
    for (int a = 0; a < H; ++a)
#pragma unroll
        for (int b = 0; b < H; ++b) {
            const float v = wave_reduce(m[a][b]);
            if (lane == 0) sm[wv][a * H + b] = v;
        }
    __syncthreads();
    if (t < 25)
        Mp[blockIdx.x * 25 + t] = sm[0][t] + sm[1][t] + sm[2][t] + sm[3][t];
}

// Lane-parallel rotation, compile-time (p,q). Lane L (<25) holds
// a = A[L/5][L%5], u = U[L/5][L%5]. Rolled sweep loop keeps code tiny.
#define JROT(p, q)                                                            \
    {                                                                         \
        const float apq = __shfl(a, (p) * 5 + (q), 64);                       \
        const float app = __shfl(a, (p) * 5 + (p), 64);                       \
        const float aqq = __shfl(a, (q) * 5 + (q), 64);                       \
        const bool  skip =                                                    \
            (apq * apq) <= (1e-26f * (app * app + aqq * aqq) + 1e-38f);       \
        const float theta = (aqq - app) * frcp(2.0f * apq);                   \
        const float tden  = fabsf(theta) + sqrtf(theta * theta + 1.0f);       \
        const float ttv   = ((theta >= 0.0f) ? 1.0f : -1.0f) * frcp(tden);    \
        float cc = frsq(ttv * ttv + 1.0f);                                    \
        float ss = ttv * cc;                                                  \
        cc = skip ? 1.0f : cc;                                                \
        ss = skip ? 0.0f : ss;                                                \
        /* row phase: A <- R^T A (rows p,q) */                                \
        {                                                                     \
            const int  pr   = ((r == (p)) ? (q) : ((r == (q)) ? (p) : r));    \
            const float prt = __shfl(a, pr * 5 + c, 64);                      \
            a = (r == (p)) ? (cc * a - ss * prt)                              \
                           : ((r == (q)) ? (ss * prt + cc * a) : a);          \
        }                                                                     \
        /* col phase: A <- A R (cols p,q) */                                  \
        {                                                                     \
            const int  pc   = ((c == (p)) ? (q) : ((c == (q)) ? (p) : c));    \
            const float prt = __shfl(a, r * 5 + pc, 64);                      \
            a = (c == (p)) ? (cc * a - ss * prt)                              \
                           : ((c == (q)) ? (ss * prt + cc * a) : a);          \
            const float urt = __shfl(u, r * 5 + pc, 64);                      \
            u = (c == (p)) ? (cc * u - ss * urt)                              \
                           : ((c == (q)) ? (ss * urt + cc * u) : u);          \
        }                                                                     \
    }

// One block: reduce 512 partial Ms -> M; A = M M^T distributed one element
// per lane of wave 0; 6 rolled sweeps of lane-parallel Jacobi;
// yp = U max(sqrt(lam),eps) U^T - eps*I (25 floats).
__global__ __launch_bounds__(256) void k_small(const float* __restrict__ Mp,
                                               float* __restrict__ yp) {
    __shared__ float sred[10][26];
    __shared__ float Msum[25];
    const int t = threadIdx.x;

    if (t < 250) {
        const int e = t % 25, g = t / 25;
        float s = 0.f;
#pragma unroll 4
        for (int p = g; p < NBLK; p += 10) s += Mp[p * 25 + e];
        sred[g][e] = s;
    }
    __syncthreads();
    if (t < 25) {
        float s = 0.f;
#pragma unroll
        for (int g = 0; g < 10; ++g) s += sred[g][t];
        Msum[t] = s;
    }
    __syncthreads();

    if (t < 64) {
        const int r = t / 5, c = t % 5;          // valid for t<25; benign above
        const float m = (t < 25) ? Msum[t] : 0.f;

        // A = M M^T : A[r][c] = sum_k M[r][k] * M[c][k]
        float a = 0.f;
#pragma unroll
        for (int k = 0; k < H; ++k)
            a += __shfl(m, r * 5 + k, 64) * __shfl(m, c * 5 + k, 64);
        float u = (t < 25 && r == c) ? 1.0f : 0.0f;

        for (int sweep = 0; sweep < 6; ++sweep) {
            JROT(0, 1) JROT(0, 2) JROT(0, 3) JROT(0, 4) JROT(1, 2)
            JROT(1, 3) JROT(1, 4) JROT(2, 3) JROT(2, 4) JROT(3, 4)
        }

        // per-lane eigenvalue candidate (only diagonal lanes 0,6,12,18,24 used)
        const float ev = fmaxf(sqrtf(fmaxf(a, 0.0f)), FEPS);
        float yv = 0.f;
#pragma unroll
        for (int k = 0; k < H; ++k) {
            const float evk = __shfl(ev, 6 * k, 64);
            const float urk = __shfl(u, r * 5 + k, 64);
            const float uck = __shfl(u, c * 5 + k, 64);
            yv += evk * urk * uck;
        }
        if (t < 25) yp[t] = yv - ((r == c) ? FEPS : 0.f);
    }
}

// z[i][j] = sum_m c[m]*W2[m][j] + eps*delta_ij,  c[m] = sum_k W2[k][i]*yp[k][m]
__global__ __launch_bounds__(256) void k_out(const float* __restrict__ W2,
                                             const float* __restrict__ yp,
                                             float* __restrict__ Z) {
    const int i = blockIdx.x;
    const int t = threadIdx.x;

    float wcol[H];
#pragma unroll
    for (int k = 0; k < H; ++k) wcol[k] = W2[(size_t)k * NO + i];
    float c[H];
#pragma unroll
    for (int m = 0; m < H; ++m) {
        float s = 0.f;
#pragma unroll
        for (int k = 0; k < H; ++k) s += wcol[k] * yp[k * H + m];
        c[m] = s;
    }

#pragma unroll
    for (int hh = 0; hh < 2; ++hh) {
        const int jj = (hh * 256 + t) * 4;
        float zx = 0.f, zy = 0.f, zz = 0.f, zw = 0.f;
#pragma unroll
        for (int m = 0; m < H; ++m) {
            const float4 b = *reinterpret_cast<const float4*>(W2 + (size_t)m * NO + jj);
            zx += c[m] * b.x;
            zy += c[m] * b.y;
            zz += c[m] * b.z;
            zw += c[m] * b.w;
        }
        zx += (i == jj + 0) ? FEPS : 0.f;
        zy += (i == jj + 1) ? FEPS : 0.f;
        zz += (i == jj + 2) ? FEPS : 0.f;
        zw += (i == jj + 3) ? FEPS : 0.f;
        float4 o = make_float4(zx, zy, zz, zw);
        *reinterpret_cast<float4*>(Z + (size_t)i * NO + jj) = o;
    }
}

extern "C" void kernel_launch(void* const* d_in, const int* in_sizes, int n_in,
                              void* d_out, int out_size, void* d_ws, size_t ws_size,
                              hipStream_t stream) {
    const float* X  = (const float*)d_in[0];
    const float* W1 = (const float*)d_in[1];
    const float* W2 = (const float*)d_in[2];
    float* out = (float*)d_out;
    float* ws  = (float*)d_ws;

    float* Mp = ws;              // NBLK*25
    float* yp = ws + NBLK * 25;  // 25

    hipLaunchKernelGGL(k_xw1,   dim3(NBLK), dim3(256), 0, stream, X, W1, Mp);
    hipLaunchKernelGGL(k_small, dim3(1),    dim3(256), 0, stream, Mp, yp);
    hipLaunchKernelGGL(k_out,   dim3(NO),   dim3(256), 0, stream, W2, yp, out);
}

// Round 5
// 43.951 us; speedup vs baseline: 1.7284x; 1.1011x over previous
//
#include <hip/hip_runtime.h>
#include <math.h>

static constexpr int N   = 4096;  // IN_SIZE
static constexpr int H   = 5;     // HID
static constexpr int NO  = 2048;  // OUT_SIZE
static constexpr float FEPS = 1e-4f;
static constexpr int RPB  = 8;        // X rows per block in k_xw1
static constexpr int NBLK = N / RPB;  // 512
static constexpr int NR   = 8;        // output rows per block in k_out (256 blocks)

#if __has_builtin(__builtin_amdgcn_rcpf)
__device__ __forceinline__ float frcp(float x) { return __builtin_amdgcn_rcpf(x); }
#else
__device__ __forceinline__ float frcp(float x) { return 1.0f / x; }
#endif
#if __has_builtin(__builtin_amdgcn_rsqf)
__device__ __forceinline__ float frsq(float x) { return __builtin_amdgcn_rsqf(x); }
#else
__device__ __forceinline__ float frsq(float x) { return 1.0f / sqrtf(x); }
#endif

__device__ __forceinline__ float wave_reduce(float v) {
#pragma unroll
    for (int o = 32; o > 0; o >>= 1) v += __shfl_down(v, o, 64);
    return v;
}

// K1: per-block partial of M = W1^T (X W1). Each block handles 8 rows of X,
// folds per-thread partial T directly into a 5x5 partial M, block-reduces,
// writes 25 floats. X read exactly once (67 MB) -> HBM-bound.
__global__ __launch_bounds__(256) void k_xw1(const float* __restrict__ X,
                                             const float* __restrict__ W1,
                                             float* __restrict__ Mp) {
    const int rb = blockIdx.x * RPB;
    const int t  = threadIdx.x;
    const float4* W14 = reinterpret_cast<const float4*>(W1);

    float acc[RPB][H];
#pragma unroll
    for (int r = 0; r < RPB; ++r)
#pragma unroll
        for (int a = 0; a < H; ++a) acc[r][a] = 0.f;

#pragma unroll
    for (int c = 0; c < 4; ++c) {
        const int j4 = c * 256 + t;   // float4 idx within row; W1 rows 4j4..4j4+3
        float wf[20];
        {
            const float4 f0 = W14[5 * j4 + 0];
            const float4 f1 = W14[5 * j4 + 1];
            const float4 f2 = W14[5 * j4 + 2];
            const float4 f3 = W14[5 * j4 + 3];
            const float4 f4 = W14[5 * j4 + 4];
            wf[0]=f0.x;  wf[1]=f0.y;  wf[2]=f0.z;  wf[3]=f0.w;
            wf[4]=f1.x;  wf[5]=f1.y;  wf[6]=f1.z;  wf[7]=f1.w;
            wf[8]=f2.x;  wf[9]=f2.y;  wf[10]=f2.z; wf[11]=f2.w;
            wf[12]=f3.x; wf[13]=f3.y; wf[14]=f3.z; wf[15]=f3.w;
            wf[16]=f4.x; wf[17]=f4.y; wf[18]=f4.z; wf[19]=f4.w;
        }
#pragma unroll
        for (int r = 0; r < RPB; ++r) {
            const float4 x = reinterpret_cast<const float4*>(
                                 X + (size_t)(rb + r) * N)[j4];
#pragma unroll
            for (int a = 0; a < H; ++a)
                acc[r][a] += x.x * wf[a]      + x.y * wf[5 + a]
                           + x.z * wf[10 + a] + x.w * wf[15 + a];
        }
    }

    float m[H][H];
#pragma unroll
    for (int a = 0; a < H; ++a)
#pragma unroll
        for (int b = 0; b < H; ++b) m[a][b] = 0.f;
#pragma unroll
    for (int r = 0; r < RPB; ++r) {
        float w1r[H];
#pragma unroll
        for (int a = 0; a < H; ++a) w1r[a] = W1[(size_t)(rb + r) * H + a];
#pragma unroll
        for (int a = 0; a < H; ++a)
#pragma unroll
            for (int b = 0; b < H; ++b) m[a][b] += w1r[a] * acc[r][b];
    }

    __shared__ float sm[4][25];
    const int lane = t & 63, wv = t >> 6;
#pragma unroll
    for (int a = 0; a < H; ++a)
#pragma unroll
        for (int b = 0; b < H; ++b) {
            const float v = wave_reduce(m[a][b]);
            if (lane == 0) sm[wv][a * H + b] = v;
        }
    __syncthreads();
    if (t < 25)
        Mp[blockIdx.x * 25 + t] = sm[0][t] + sm[1][t] + sm[2][t] + sm[3][t];
}

// Lane-parallel Jacobi rotation, compile-time (p,q). Lane L (<25) holds
// a = A[L/5][L%5], u = U[L/5][L%5].
#define JROT(p, q)                                                            \
    {                                                                         \
        const float apq = __shfl(a, (p) * 5 + (q), 64);                       \
        const float app = __shfl(a, (p) * 5 + (p), 64);                       \
        const float aqq = __shfl(a, (q) * 5 + (q), 64);                       \
        const bool  skip =                                                    \
            (apq * apq) <= (1e-26f * (app * app + aqq * aqq) + 1e-38f);       \
        const float theta = (aqq - app) * frcp(2.0f * apq);                   \
        const float tden  = fabsf(theta) + sqrtf(theta * theta + 1.0f);       \
        const float ttv   = ((theta >= 0.0f) ? 1.0f : -1.0f) * frcp(tden);    \
        float cc = frsq(ttv * ttv + 1.0f);                                    \
        float ss = ttv * cc;                                                  \
        cc = skip ? 1.0f : cc;                                                \
        ss = skip ? 0.0f : ss;                                                \
        {                                                                     \
            const int  pr   = ((r == (p)) ? (q) : ((r == (q)) ? (p) : r));    \
            const float prt = __shfl(a, pr * 5 + c, 64);                      \
            a = (r == (p)) ? (cc * a - ss * prt)                              \
                           : ((r == (q)) ? (ss * prt + cc * a) : a);          \
        }                                                                     \
        {                                                                     \
            const int  pc   = ((c == (p)) ? (q) : ((c == (q)) ? (p) : c));    \
            const float prt = __shfl(a, r * 5 + pc, 64);                      \
            a = (c == (p)) ? (cc * a - ss * prt)                              \
                           : ((c == (q)) ? (ss * prt + cc * a) : a);          \
            const float urt = __shfl(u, r * 5 + pc, 64);                      \
            u = (c == (p)) ? (cc * u - ss * urt)                              \
                           : ((c == (q)) ? (ss * urt + cc * u) : u);          \
        }                                                                     \
    }

// K2: 256 blocks, NR=8 output rows each. Every block redundantly:
//   (1) reduces Mp -> M (51 KB, L2/L3-hit after first touch)
//   (2) wave0: A = M M^T, 6 sweeps lane-parallel Jacobi, ys = U e U^T - eps*I
//   (3) z[i][j] = sum_m c[r][m]*W2[m][j] + eps*delta, 8 rows per block,
//       W2 j-slices loaded once per block and reused across the 8 rows.
// Bit-identical per block -> deterministic. No atomics/fences needed.
__global__ __launch_bounds__(256) void k_out(const float* __restrict__ Mp,
                                             const float* __restrict__ W2,
                                             float* __restrict__ Z) {
    __shared__ float sred[10][26];
    __shared__ float Msum[25];
    __shared__ float ys[25];
    const int t = threadIdx.x;

    // (1) reduce partial Ms
    if (t < 250) {
        const int e = t % 25, g = t / 25;
        float s = 0.f;
#pragma unroll 8
        for (int p = g; p < NBLK; p += 10) s += Mp[p * 25 + e];
        sred[g][e] = s;
    }
    __syncthreads();
    if (t < 25) {
        float s = 0.f;
#pragma unroll
        for (int g = 0; g < 10; ++g) s += sred[g][t];
        Msum[t] = s;
    }
    __syncthreads();

    // (2) eigensolve on wave 0
    if (t < 64) {
        const int r = t / 5, c = t % 5;
        const float m = (t < 25) ? Msum[t] : 0.f;
        float a = 0.f;
#pragma unroll
        for (int k = 0; k < H; ++k)
            a += __shfl(m, r * 5 + k, 64) * __shfl(m, c * 5 + k, 64);
        float u = (t < 25 && r == c) ? 1.0f : 0.0f;

        for (int sweep = 0; sweep < 6; ++sweep) {
            JROT(0, 1) JROT(0, 2) JROT(0, 3) JROT(0, 4) JROT(1, 2)
            JROT(1, 3) JROT(1, 4) JROT(2, 3) JROT(2, 4) JROT(3, 4)
        }

        const float ev = fmaxf(sqrtf(fmaxf(a, 0.0f)), FEPS);
        float yv = 0.f;
#pragma unroll
        for (int k = 0; k < H; ++k) {
            const float evk = __shfl(ev, 6 * k, 64);
            const float urk = __shfl(u, r * 5 + k, 64);
            const float uck = __shfl(u, c * 5 + k, 64);
            yv += evk * urk * uck;
        }
        if (t < 25) ys[t] = yv - ((r == c) ? FEPS : 0.f);
    }
    __syncthreads();

    // (3) output: rows i0..i0+7
    const int i0 = blockIdx.x * NR;
    float cmat[NR][H];
#pragma unroll
    for (int r = 0; r < NR; ++r) {
        float wcol[H];
#pragma unroll
        for (int k = 0; k < H; ++k) wcol[k] = W2[(size_t)k * NO + i0 + r];
#pragma unroll
        for (int m = 0; m < H; ++m) {
            float s = 0.f;
#pragma unroll
            for (int k = 0; k < H; ++k) s += wcol[k] * ys[k * H + m];
            cmat[r][m] = s;
        }
    }

#pragma unroll
    for (int hh = 0; hh < 2; ++hh) {
        const int jj = (hh * 256 + t) * 4;
        float4 w2j[H];
#pragma unroll
        for (int m = 0; m < H; ++m)
            w2j[m] = *reinterpret_cast<const float4*>(W2 + (size_t)m * NO + jj);
#pragma unroll
        for (int r = 0; r < NR; ++r) {
            const int i = i0 + r;
            float zx = 0.f, zy = 0.f, zz = 0.f, zw = 0.f;
#pragma unroll
            for (int m = 0; m < H; ++m) {
                const float cm = cmat[r][m];
                zx += cm * w2j[m].x;
                zy += cm * w2j[m].y;
                zz += cm * w2j[m].z;
                zw += cm * w2j[m].w;
            }
            if (i >= jj && i < jj + 4) {
                if      (i == jj + 0) zx += FEPS;
                else if (i == jj + 1) zy += FEPS;
                else if (i == jj + 2) zz += FEPS;
                else                  zw += FEPS;
            }
            *reinterpret_cast<float4*>(Z + (size_t)i * NO + jj) =
                make_float4(zx, zy, zz, zw);
        }
    }
}

extern "C" void kernel_launch(void* const* d_in, const int* in_sizes, int n_in,
                              void* d_out, int out_size, void* d_ws, size_t ws_size,
                              hipStream_t stream) {
    const float* X  = (const float*)d_in[0];
    const float* W1 = (const float*)d_in[1];
    const float* W2 = (const float*)d_in[2];
    float* out = (float*)d_out;
    float* ws  = (float*)d_ws;

    float* Mp = ws;   // NBLK*25 floats

    hipLaunchKernelGGL(k_xw1, dim3(NBLK),    dim3(256), 0, stream, X, W1, Mp);
    hipLaunchKernelGGL(k_out, dim3(NO / NR), dim3(256), 0, stream, Mp, W2, out);
}